// Round 2
// baseline (556.339 us; speedup 1.0000x reference)
//
#include <hip/hip_runtime.h>
#include <cstdint>
#include <cstddef>

#define T_ 2048
#define D_ 2048
#define E_ 16
#define F_ 512

typedef unsigned short u16;
typedef unsigned int u32;
typedef __attribute__((ext_vector_type(8))) short bf16x8;
typedef __attribute__((ext_vector_type(4))) short bf16x4;
typedef __attribute__((ext_vector_type(4))) float f32x4;
typedef __attribute__((ext_vector_type(2))) u32 u32x2;
typedef __attribute__((ext_vector_type(8))) u16 u16x8;

__device__ __forceinline__ u16 f2bf(float f){
  union { float f; u32 u; } c; c.f = f;
  return (u16)((c.u + 0x7FFFu + ((c.u >> 16) & 1u)) >> 16);
}

__device__ __forceinline__ void gload16(const void* g, void* l){
  __builtin_amdgcn_global_load_lds((const __attribute__((address_space(1))) void*)g,
                                   (__attribute__((address_space(3))) void*)l,
                                   16, 0, 0);
}

__device__ __forceinline__ u32 lds_off(const void* p){
  return (u32)(uintptr_t)(const __attribute__((address_space(3))) void*)p;
}

__device__ __forceinline__ u32x2 tr8(u32 addr){
  u32x2 r;
  asm volatile("ds_read_b64_tr_b16 %0, %1" : "=v"(r) : "v"(addr));
  return r;
}

__device__ __forceinline__ bf16x8 mk8(u32x2 lo, u32x2 hi){
  bf16x4 a = __builtin_bit_cast(bf16x4, lo);
  bf16x4 b = __builtin_bit_cast(bf16x4, hi);
  return __builtin_shufflevector(a, b, 0,1,2,3,4,5,6,7);
}

__device__ __forceinline__ void st4(u16* p, float4 v){
  u32 lo = (u32)f2bf(v.x) | ((u32)f2bf(v.y) << 16);
  u32 hi = (u32)f2bf(v.z) | ((u32)f2bf(v.w) << 16);
  u32x2 u = {lo, hi};
  *(u32x2*)p = u;
}

// ---------------- K1: rmsnorm + router (fp32) + scatter ----------------
__global__ __launch_bounds__(256) void k_norm_router(
    const float* __restrict__ x, const float* __restrict__ nw, const float* __restrict__ gw,
    u16* __restrict__ h, int* __restrict__ counts, int* __restrict__ eidx, float* __restrict__ ew)
{
  const int t = blockIdx.x, tid = threadIdx.x;
  const int lane = tid & 63, wid = tid >> 6;
  const int d0 = tid * 8;
  const float4 v0 = *(const float4*)(x + (size_t)t*D_ + d0);
  const float4 v1 = *(const float4*)(x + (size_t)t*D_ + d0 + 4);
  float hv[8] = {v0.x, v0.y, v0.z, v0.w, v1.x, v1.y, v1.z, v1.w};
  float ss = 0.f;
  #pragma unroll
  for (int j = 0; j < 8; ++j) ss += hv[j]*hv[j];
  #pragma unroll
  for (int o = 32; o; o >>= 1) ss += __shfl_xor(ss, o);
  __shared__ float sred[4];
  __shared__ float red16[4][16];
  __shared__ float lf[16];
  if (lane == 0) sred[wid] = ss;
  __syncthreads();
  const float rstd = rsqrtf((sred[0]+sred[1]+sred[2]+sred[3]) * (1.f/(float)D_) + 1e-6f);
  const float4 w0 = *(const float4*)(nw + d0);
  const float4 w1 = *(const float4*)(nw + d0 + 4);
  const float wv[8] = {w0.x,w0.y,w0.z,w0.w,w1.x,w1.y,w1.z,w1.w};
  #pragma unroll
  for (int j = 0; j < 8; ++j) hv[j] = hv[j] * rstd * wv[j];
  u16x8 hb;
  #pragma unroll
  for (int j = 0; j < 8; ++j) hb[j] = f2bf(hv[j]);
  *(u16x8*)(h + (size_t)t*D_ + d0) = hb;

  float lg[16];
  #pragma unroll
  for (int e = 0; e < 16; ++e){
    const float4 g0 = *(const float4*)(gw + e*D_ + d0);
    const float4 g1 = *(const float4*)(gw + e*D_ + d0 + 4);
    lg[e] = hv[0]*g0.x + hv[1]*g0.y + hv[2]*g0.z + hv[3]*g0.w
          + hv[4]*g1.x + hv[5]*g1.y + hv[6]*g1.z + hv[7]*g1.w;
  }
  #pragma unroll
  for (int e = 0; e < 16; ++e){
    #pragma unroll
    for (int o = 32; o; o >>= 1) lg[e] += __shfl_xor(lg[e], o);
  }
  if (lane == 0){
    #pragma unroll
    for (int e = 0; e < 16; ++e) red16[wid][e] = lg[e];
  }
  __syncthreads();
  if (tid < 16) lf[tid] = red16[0][tid] + red16[1][tid] + red16[2][tid] + red16[3][tid];
  __syncthreads();
  if (tid == 0){
    float l[16];
    #pragma unroll
    for (int e = 0; e < 16; ++e) l[e] = lf[e];
    int sel[4]; float sv[4]; u32 used = 0;
    for (int k = 0; k < 4; ++k){
      float b = -3.4e38f; int bi = 0;
      for (int e = 0; e < 16; ++e)
        if (!((used >> e) & 1u) && l[e] > b){ b = l[e]; bi = e; }
      used |= 1u << bi; sel[k] = bi; sv[k] = b;
    }
    float ex[4]; float s = 0.f;
    for (int k = 0; k < 4; ++k){ ex[k] = __expf(sv[k] - sv[0]); s += ex[k]; }
    const float inv = 1.f / s;
    for (int k = 0; k < 4; ++k){
      const int e = sel[k];
      const int pos = atomicAdd(&counts[e], 1);
      eidx[e*T_ + pos] = t;
      ew[e*T_ + pos] = ex[k] * inv;
    }
  }
}

// ---------------- K2: out = residual ----------------
__global__ __launch_bounds__(256) void k_copy(const float4* __restrict__ s, float4* __restrict__ d)
{
  const int i = blockIdx.x * 256 + threadIdx.x;
  d[i] = s[i];
}

// ---------------- K3: gate/up GEMM + silu*up, act (weighted) to ws ----------------
// grid: x = token-tile (16), y = f-tile (8), z = expert (16). 256 threads.
// Weight LDS tile: row-major [k=0..31][f=0..63], row stride S3=68 elements.
__global__ __launch_bounds__(256) void k_gateup(
    const u16* __restrict__ h, const float* __restrict__ wg, const float* __restrict__ wu,
    const int* __restrict__ counts, const int* __restrict__ eidx, const float* __restrict__ ew,
    u16* __restrict__ act)
{
  const int tt = blockIdx.x, ft = blockIdx.y, e = blockIdx.z;
  const int cnt = counts[e];
  const int row0 = tt * 128;
  if (row0 >= cnt) return;
  int abase = 0;
  for (int i = 0; i < e; ++i) abase += counts[i];

  const int tid = threadIdx.x, lane = tid & 63, wid = tid >> 6;
  const int f0 = ft * 64;

  __shared__ __align__(16) u16 Xs[128*32];
  __shared__ __align__(16) u16 Wgs[2176];   // 32 rows x stride 68
  __shared__ __align__(16) u16 Wus[2176];
  __shared__ int   toks[128];
  __shared__ float tws[128];

  if (tid < 128){
    int slot = row0 + tid;
    int cs = slot < cnt ? slot : (cnt - 1);
    toks[tid] = eidx[e*T_ + cs];
    tws[tid]  = slot < cnt ? ew[e*T_ + slot] : 0.f;
  }
  __syncthreads();

  // X staging (global_load_lds, pre-swizzled global source; LDS row-major [row][32k])
  const int rA = wid*32 + (lane >> 2);
  const int rB = rA + 16;
  const int gA = (lane & 3) ^ (rA & 3);
  const int gB = (lane & 3) ^ (rB & 3);
  const u16* srcA = h + (size_t)toks[rA]*D_ + 8*gA;
  const u16* srcB = h + (size_t)toks[rB]*D_ + 8*gB;
  void* dstA = (void*)&Xs[(wid*32    )*32];
  void* dstB = (void*)&Xs[(wid*32 +16)*32];

  // W staging: chunk c -> k = c>>4 (c0:0..15, c1:16..31), f4 = (c&15)*4
  const int k0c = tid >> 4,        f40 = (tid & 15) * 4;
  const int k1c = (tid >> 4) + 16, f41 = f40;
  const size_t wbase = (size_t)e * D_ * F_;
  const u32 widx0 = (u32)(k0c*68 + f40);
  const u32 widx1 = (u32)(k1c*68 + f41);

  // tr-read lane base: group g = lane>>4, p = lane&15
  // lane addr(ni) = ((8g + (p>>2))*68 + 4*(p&3))*2 + 32*ni ; 2nd read +544 B (4 rows)
  const int p_ = lane & 15, g_ = lane >> 4;
  const u32 trb = (u32)((8*g_ + (p_ >> 2))*68 + 4*(p_ & 3)) * 2u;
  const u32 wgof = lds_off(Wgs) + trb, wuof = lds_off(Wus) + trb;

  const int axor = g_ ^ (lane & 3);
  const u32 aoff0 = (u32)(wid*32 + p_)*32 + 8u*(u32)axor;
  const u32 aoff1 = aoff0 + 512;

  f32x4 accg[2][4] = {};
  f32x4 accu[2][4] = {};

  for (int kt = 0; kt < 64; ++kt){
    const int kb = kt * 32;
    gload16(srcA + kb, dstA);
    gload16(srcB + kb, dstB);

    const float4 vg0 = *(const float4*)(wg + wbase + (size_t)(kb + k0c)*F_ + f0 + f40);
    const float4 vu0 = *(const float4*)(wu + wbase + (size_t)(kb + k0c)*F_ + f0 + f40);
    const float4 vg1 = *(const float4*)(wg + wbase + (size_t)(kb + k1c)*F_ + f0 + f41);
    const float4 vu1 = *(const float4*)(wu + wbase + (size_t)(kb + k1c)*F_ + f0 + f41);
    st4(&Wgs[widx0], vg0); st4(&Wus[widx0], vu0);
    st4(&Wgs[widx1], vg1); st4(&Wus[widx1], vu1);
    __syncthreads();

    const bf16x8 a0 = *(const bf16x8*)&Xs[aoff0];
    const bf16x8 a1 = *(const bf16x8*)&Xs[aoff1];
    u32x2 tg[4][2], tu[4][2];
    #pragma unroll
    for (int ni = 0; ni < 4; ++ni){
      tg[ni][0] = tr8(wgof + 32u*ni);
      tg[ni][1] = tr8(wgof + 32u*ni + 544u);
      tu[ni][0] = tr8(wuof + 32u*ni);
      tu[ni][1] = tr8(wuof + 32u*ni + 544u);
    }
    asm volatile("s_waitcnt lgkmcnt(0)" ::: "memory");
    __builtin_amdgcn_sched_barrier(0);
    #pragma unroll
    for (int ni = 0; ni < 4; ++ni){
      const bf16x8 bg = mk8(tg[ni][0], tg[ni][1]);
      const bf16x8 bu = mk8(tu[ni][0], tu[ni][1]);
      accg[0][ni] = __builtin_amdgcn_mfma_f32_16x16x32_bf16(a0, bg, accg[0][ni], 0, 0, 0);
      accg[1][ni] = __builtin_amdgcn_mfma_f32_16x16x32_bf16(a1, bg, accg[1][ni], 0, 0, 0);
      accu[0][ni] = __builtin_amdgcn_mfma_f32_16x16x32_bf16(a0, bu, accu[0][ni], 0, 0, 0);
      accu[1][ni] = __builtin_amdgcn_mfma_f32_16x16x32_bf16(a1, bu, accu[1][ni], 0, 0, 0);
    }
    __syncthreads();
  }

  const int cr = lane >> 4, cc = lane & 15;
  #pragma unroll
  for (int mi = 0; mi < 2; ++mi)
  #pragma unroll
  for (int ni = 0; ni < 4; ++ni)
  #pragma unroll
  for (int r = 0; r < 4; ++r){
    const int row  = wid*32 + mi*16 + cr*4 + r;
    const int slot = row0 + row;
    if (slot < cnt){
      const float gv = accg[mi][ni][r], uv = accu[mi][ni][r];
      const float a = tws[row] * (gv / (1.f + __expf(-gv))) * uv;
      act[(size_t)(abase + slot)*F_ + f0 + ni*16 + cc] = f2bf(a);
    }
  }
}

// ---------------- K4: down GEMM, atomicAdd into out ----------------
// grid: x = token-tile (16), y = d-tile (16), z = expert (16). 256 threads.
// Weight LDS tile: row-major [k=0..31][d=0..127], row stride S4=136 elements.
__global__ __launch_bounds__(256) void k_down(
    const u16* __restrict__ act, const float* __restrict__ wd,
    const int* __restrict__ counts, const int* __restrict__ eidx,
    float* __restrict__ out)
{
  const int tt = blockIdx.x, dt = blockIdx.y, e = blockIdx.z;
  const int cnt = counts[e];
  const int row0 = tt * 128;
  if (row0 >= cnt) return;
  int abase = 0;
  for (int i = 0; i < e; ++i) abase += counts[i];

  const int tid = threadIdx.x, lane = tid & 63, wid = tid >> 6;
  const int d0 = dt * 128;

  __shared__ __align__(16) u16 As[128*32];
  __shared__ __align__(16) u16 Wds[4352];   // 32 rows x stride 136
  __shared__ int toks[128];

  if (tid < 128){
    int slot = row0 + tid;
    toks[tid] = slot < cnt ? eidx[e*T_ + slot] : -1;
  }
  __syncthreads();

  const int rA = wid*32 + (lane >> 2);
  const int rB = rA + 16;
  const int gA = (lane & 3) ^ (rA & 3);
  const int gB = (lane & 3) ^ (rB & 3);
  const u16* srcA = act + (size_t)(abase + row0 + rA)*F_ + 8*gA;
  const u16* srcB = act + (size_t)(abase + row0 + rB)*F_ + 8*gB;
  void* dstA = (void*)&As[(wid*32    )*32];
  void* dstB = (void*)&As[(wid*32 +16)*32];

  const size_t wbase = (size_t)e * F_ * D_;
  int kc[4], dl4[4]; u32 wix[4];
  #pragma unroll
  for (int m = 0; m < 4; ++m){
    const int c = tid + m*256;
    kc[m] = c >> 5; dl4[m] = (c & 31) * 4;
    wix[m] = (u32)(kc[m]*136 + dl4[m]);
  }

  const int p_ = lane & 15, g_ = lane >> 4;
  const u32 trb = (u32)((8*g_ + (p_ >> 2))*136 + 4*(p_ & 3)) * 2u;
  const u32 wdof = lds_off(Wds) + trb;

  const int axor = g_ ^ (lane & 3);
  const u32 aoff0 = (u32)(wid*32 + p_)*32 + 8u*(u32)axor;
  const u32 aoff1 = aoff0 + 512;

  f32x4 acc[2][8] = {};

  for (int kt = 0; kt < 16; ++kt){
    const int kb = kt * 32;
    gload16(srcA + kb, dstA);
    gload16(srcB + kb, dstB);
    #pragma unroll
    for (int m = 0; m < 4; ++m){
      const float4 v = *(const float4*)(wd + wbase + (size_t)(kb + kc[m])*D_ + d0 + dl4[m]);
      st4(&Wds[wix[m]], v);
    }
    __syncthreads();

    const bf16x8 a0 = *(const bf16x8*)&As[aoff0];
    const bf16x8 a1 = *(const bf16x8*)&As[aoff1];
    u32x2 tb[8][2];
    #pragma unroll
    for (int ni = 0; ni < 8; ++ni){
      tb[ni][0] = tr8(wdof + 32u*ni);
      tb[ni][1] = tr8(wdof + 32u*ni + 1088u);
    }
    asm volatile("s_waitcnt lgkmcnt(0)" ::: "memory");
    __builtin_amdgcn_sched_barrier(0);
    #pragma unroll
    for (int ni = 0; ni < 8; ++ni){
      const bf16x8 b = mk8(tb[ni][0], tb[ni][1]);
      acc[0][ni] = __builtin_amdgcn_mfma_f32_16x16x32_bf16(a0, b, acc[0][ni], 0, 0, 0);
      acc[1][ni] = __builtin_amdgcn_mfma_f32_16x16x32_bf16(a1, b, acc[1][ni], 0, 0, 0);
    }
    __syncthreads();
  }

  const int cr = lane >> 4, cc = lane & 15;
  #pragma unroll
  for (int mi = 0; mi < 2; ++mi)
  #pragma unroll
  for (int ni = 0; ni < 8; ++ni)
  #pragma unroll
  for (int r = 0; r < 4; ++r){
    const int row = wid*32 + mi*16 + cr*4 + r;
    const int tok = toks[row];
    if (tok >= 0)
      atomicAdd(out + (size_t)tok*D_ + d0 + ni*16 + cc, acc[mi][ni][r]);
  }
}

extern "C" void kernel_launch(void* const* d_in, const int* in_sizes, int n_in,
                              void* d_out, int out_size, void* d_ws, size_t ws_size,
                              hipStream_t stream)
{
  (void)in_sizes; (void)n_in; (void)out_size; (void)ws_size;
  const float* x     = (const float*)d_in[0];
  const float* nw    = (const float*)d_in[1];
  const float* gw    = (const float*)d_in[2];
  const float* wgate = (const float*)d_in[3];
  const float* wup   = (const float*)d_in[4];
  const float* wdown = (const float*)d_in[5];
  float* out = (float*)d_out;

  char* ws = (char*)d_ws;
  u16*   h      = (u16*)(ws);                       // 8,388,608 B
  u16*   act    = (u16*)(ws + 8388608);             // 8,519,680 B (8192+128 rows x 512 bf16)
  int*   counts = (int*)(ws + 16908288);            // 64 B
  int*   eidx   = (int*)(ws + 16908352);            // 131,072 B
  float* ew     = (float*)(ws + 17039424);          // 131,072 B

  hipMemsetAsync(counts, 0, 64, stream);
  k_norm_router<<<T_, 256, 0, stream>>>(x, nw, gw, h, counts, eidx, ew);
  k_copy<<<(T_*D_)/4/256, 256, 0, stream>>>((const float4*)x, (float4*)out);
  k_gateup<<<dim3(16, 8, 16), 256, 0, stream>>>(h, wgate, wup, counts, eidx, ew, act);
  k_down<<<dim3(16, 16, 16), 256, 0, stream>>>(act, wdown, counts, eidx, out);
}

// Round 3
// 340.583 us; speedup vs baseline: 1.6335x; 1.6335x over previous
//
#include <hip/hip_runtime.h>
#include <cstdint>
#include <cstddef>

#define T_ 2048
#define D_ 2048
#define E_ 16
#define F_ 512

typedef unsigned short u16;
typedef unsigned int u32;
typedef __attribute__((ext_vector_type(8))) short bf16x8;
typedef __attribute__((ext_vector_type(4))) short bf16x4;
typedef __attribute__((ext_vector_type(4))) float f32x4;
typedef __attribute__((ext_vector_type(2))) u32 u32x2;
typedef __attribute__((ext_vector_type(8))) u16 u16x8;

__device__ __forceinline__ u16 f2bf(float f){
  union { float f; u32 u; } c; c.f = f;
  return (u16)((c.u + 0x7FFFu + ((c.u >> 16) & 1u)) >> 16);
}

__device__ __forceinline__ void gload16(const void* g, void* l){
  __builtin_amdgcn_global_load_lds((const __attribute__((address_space(1))) void*)g,
                                   (__attribute__((address_space(3))) void*)l,
                                   16, 0, 0);
}

__device__ __forceinline__ u32 lds_off(const void* p){
  return (u32)(uintptr_t)(const __attribute__((address_space(3))) void*)p;
}

__device__ __forceinline__ u32x2 tr8(u32 addr){
  u32x2 r;
  asm volatile("ds_read_b64_tr_b16 %0, %1" : "=v"(r) : "v"(addr));
  return r;
}

__device__ __forceinline__ bf16x8 mk8(u32x2 lo, u32x2 hi){
  bf16x4 a = __builtin_bit_cast(bf16x4, lo);
  bf16x4 b = __builtin_bit_cast(bf16x4, hi);
  return __builtin_shufflevector(a, b, 0,1,2,3,4,5,6,7);
}

__device__ __forceinline__ void st4(u16* p, float4 v){
  u32 lo = (u32)f2bf(v.x) | ((u32)f2bf(v.y) << 16);
  u32 hi = (u32)f2bf(v.z) | ((u32)f2bf(v.w) << 16);
  u32x2 u = {lo, hi};
  *(u32x2*)p = u;
}

// ---------------- K1: rmsnorm + router (fp32) + scatter ----------------
__global__ __launch_bounds__(256) void k_norm_router(
    const float* __restrict__ x, const float* __restrict__ nw, const float* __restrict__ gw,
    u16* __restrict__ h, int* __restrict__ counts, int* __restrict__ eidx, float* __restrict__ ew)
{
  const int t = blockIdx.x, tid = threadIdx.x;
  const int lane = tid & 63, wid = tid >> 6;
  const int d0 = tid * 8;
  const float4 v0 = *(const float4*)(x + (size_t)t*D_ + d0);
  const float4 v1 = *(const float4*)(x + (size_t)t*D_ + d0 + 4);
  float hv[8] = {v0.x, v0.y, v0.z, v0.w, v1.x, v1.y, v1.z, v1.w};
  float ss = 0.f;
  #pragma unroll
  for (int j = 0; j < 8; ++j) ss += hv[j]*hv[j];
  #pragma unroll
  for (int o = 32; o; o >>= 1) ss += __shfl_xor(ss, o);
  __shared__ float sred[4];
  __shared__ float red16[4][16];
  __shared__ float lf[16];
  if (lane == 0) sred[wid] = ss;
  __syncthreads();
  const float rstd = rsqrtf((sred[0]+sred[1]+sred[2]+sred[3]) * (1.f/(float)D_) + 1e-6f);
  const float4 w0 = *(const float4*)(nw + d0);
  const float4 w1 = *(const float4*)(nw + d0 + 4);
  const float wv[8] = {w0.x,w0.y,w0.z,w0.w,w1.x,w1.y,w1.z,w1.w};
  #pragma unroll
  for (int j = 0; j < 8; ++j) hv[j] = hv[j] * rstd * wv[j];
  u16x8 hb;
  #pragma unroll
  for (int j = 0; j < 8; ++j) hb[j] = f2bf(hv[j]);
  *(u16x8*)(h + (size_t)t*D_ + d0) = hb;

  float lg[16];
  #pragma unroll
  for (int e = 0; e < 16; ++e){
    const float4 g0 = *(const float4*)(gw + e*D_ + d0);
    const float4 g1 = *(const float4*)(gw + e*D_ + d0 + 4);
    lg[e] = hv[0]*g0.x + hv[1]*g0.y + hv[2]*g0.z + hv[3]*g0.w
          + hv[4]*g1.x + hv[5]*g1.y + hv[6]*g1.z + hv[7]*g1.w;
  }
  #pragma unroll
  for (int e = 0; e < 16; ++e){
    #pragma unroll
    for (int o = 32; o; o >>= 1) lg[e] += __shfl_xor(lg[e], o);
  }
  if (lane == 0){
    #pragma unroll
    for (int e = 0; e < 16; ++e) red16[wid][e] = lg[e];
  }
  __syncthreads();
  if (tid < 16) lf[tid] = red16[0][tid] + red16[1][tid] + red16[2][tid] + red16[3][tid];
  __syncthreads();
  if (tid == 0){
    float l[16];
    #pragma unroll
    for (int e = 0; e < 16; ++e) l[e] = lf[e];
    int sel[4]; float sv[4]; u32 used = 0;
    for (int k = 0; k < 4; ++k){
      float b = -3.4e38f; int bi = 0;
      for (int e = 0; e < 16; ++e)
        if (!((used >> e) & 1u) && l[e] > b){ b = l[e]; bi = e; }
      used |= 1u << bi; sel[k] = bi; sv[k] = b;
    }
    float ex[4]; float s = 0.f;
    for (int k = 0; k < 4; ++k){ ex[k] = __expf(sv[k] - sv[0]); s += ex[k]; }
    const float inv = 1.f / s;
    for (int k = 0; k < 4; ++k){
      const int e = sel[k];
      const int pos = atomicAdd(&counts[e], 1);
      eidx[e*T_ + pos] = t;
      ew[e*T_ + pos] = ex[k] * inv;
    }
  }
}

// ---------------- K2: out = residual ----------------
__global__ __launch_bounds__(256) void k_copy(const float4* __restrict__ s, float4* __restrict__ d)
{
  const int i = blockIdx.x * 256 + threadIdx.x;
  d[i] = s[i];
}

// ---------------- K3: gate/up GEMM + silu*up (2-phase pipelined) ----------------
// 2048 blocks, XCD-swizzled: bid = ((e>>3)*128 + ft*16 + tt)*8 + (e&7).
// Weight LDS tile: row-major [k=0..31][f=0..63], stride 68, double-buffered.
__global__ __launch_bounds__(256) void k_gateup(
    const u16* __restrict__ h, const float* __restrict__ wg, const float* __restrict__ wu,
    const int* __restrict__ counts, const int* __restrict__ eidx, const float* __restrict__ ew,
    u16* __restrict__ act)
{
  const int bid = blockIdx.x;
  const int e  = (bid & 7) + 8*(bid >> 10);
  const int rem = (bid >> 3) & 127;
  const int ft = rem >> 4, tt = rem & 15;

  const int cnt = counts[e];
  const int row0 = tt * 128;
  if (row0 >= cnt) return;
  int abase = 0;
  for (int i = 0; i < e; ++i) abase += counts[i];

  const int tid = threadIdx.x, lane = tid & 63, wid = tid >> 6;
  const int f0 = ft * 64;

  __shared__ __align__(16) u16 Xs[2][4096];   // [buf][128 rows x 32 k]
  __shared__ __align__(16) u16 Wgs[2][2176];  // [buf][32 rows x stride 68]
  __shared__ __align__(16) u16 Wus[2][2176];
  __shared__ int   toks[128];
  __shared__ float tws[128];

  if (tid < 128){
    int slot = row0 + tid;
    int cs = slot < cnt ? slot : (cnt - 1);
    toks[tid] = eidx[e*T_ + cs];
    tws[tid]  = slot < cnt ? ew[e*T_ + slot] : 0.f;
  }
  __syncthreads();

  // X staging (global_load_lds, pre-swizzled global source)
  const int rA = wid*32 + (lane >> 2);
  const int rB = rA + 16;
  const int gA = (lane & 3) ^ (rA & 3);
  const int gB = (lane & 3) ^ (rB & 3);
  const u16* srcA = h + (size_t)toks[rA]*D_ + 8*gA;
  const u16* srcB = h + (size_t)toks[rB]*D_ + 8*gB;
  void* dstA0 = (void*)&Xs[0][(wid*32    )*32];
  void* dstB0 = (void*)&Xs[0][(wid*32 +16)*32];
  void* dstA1 = (void*)&Xs[1][(wid*32    )*32];
  void* dstB1 = (void*)&Xs[1][(wid*32 +16)*32];

  // W staging: thread -> (k0c, f40) and (k0c+16, f40)
  const int k0c = tid >> 4, f40 = (tid & 15) * 4;
  const size_t wofs = (size_t)e * D_ * F_ + (size_t)k0c * F_ + f0 + f40;
  const u32 widx0 = (u32)(k0c*68 + f40);
  const u32 widx1 = widx0 + 16u*68u;

  // tr-read lane base
  const int p_ = lane & 15, g_ = lane >> 4;
  const u32 trb = (u32)((8*g_ + (p_ >> 2))*68 + 4*(p_ & 3)) * 2u;
  const u32 wg_of0 = lds_off(&Wgs[0][0]) + trb;
  const u32 wg_of1 = lds_off(&Wgs[1][0]) + trb;
  const u32 wu_of0 = lds_off(&Wus[0][0]) + trb;
  const u32 wu_of1 = lds_off(&Wus[1][0]) + trb;

  const int axor = g_ ^ (lane & 3);
  const u32 aoff0 = (u32)(wid*32 + p_)*32 + 8u*(u32)axor;
  const u32 aoff1 = aoff0 + 512;

  f32x4 accg[2][4] = {};
  f32x4 accu[2][4] = {};
  float4 vg0, vu0, vg1, vu1;

  // prologue: stage kt=0 into buf 0
  gload16(srcA, dstA0);
  gload16(srcB, dstB0);
  {
    const float* pg_ = wg + wofs;
    const float* pu_ = wu + wofs;
    vg0 = *(const float4*)pg_;
    vu0 = *(const float4*)pu_;
    vg1 = *(const float4*)(pg_ + 16*F_);
    vu1 = *(const float4*)(pu_ + 16*F_);
  }
  __builtin_amdgcn_sched_barrier(0);
  asm volatile("s_waitcnt vmcnt(0)");
  __builtin_amdgcn_sched_barrier(0);
  st4(&Wgs[0][widx0], vg0); st4(&Wus[0][widx0], vu0);
  st4(&Wgs[0][widx1], vg1); st4(&Wus[0][widx1], vu1);
  __syncthreads();

#define GU_STEP(CUR, NXT, KT, STAGE_NEXT) do {                                   \
    if (STAGE_NEXT){                                                             \
      const int kb2 = ((KT)+1) << 5;                                             \
      gload16(srcA + kb2, dstA##NXT);                                            \
      gload16(srcB + kb2, dstB##NXT);                                            \
      const float* pg_ = wg + wofs + (size_t)kb2 * F_;                           \
      const float* pu_ = wu + wofs + (size_t)kb2 * F_;                           \
      vg0 = *(const float4*)pg_;                                                 \
      vu0 = *(const float4*)pu_;                                                 \
      vg1 = *(const float4*)(pg_ + 16*F_);                                       \
      vu1 = *(const float4*)(pu_ + 16*F_);                                       \
    }                                                                            \
    {                                                                            \
      const bf16x8 a0 = *(const bf16x8*)&Xs[CUR][aoff0];                         \
      const bf16x8 a1 = *(const bf16x8*)&Xs[CUR][aoff1];                         \
      u32x2 tt_[4][2];                                                           \
      _Pragma("unroll")                                                          \
      for (int ni = 0; ni < 4; ++ni){                                            \
        tt_[ni][0] = tr8(wg_of##CUR + 32u*ni);                                   \
        tt_[ni][1] = tr8(wg_of##CUR + 32u*ni + 544u);                            \
      }                                                                          \
      asm volatile("s_waitcnt lgkmcnt(0)");                                      \
      __builtin_amdgcn_sched_barrier(0);                                         \
      _Pragma("unroll")                                                          \
      for (int ni = 0; ni < 4; ++ni){                                            \
        const bf16x8 bg = mk8(tt_[ni][0], tt_[ni][1]);                           \
        accg[0][ni] = __builtin_amdgcn_mfma_f32_16x16x32_bf16(a0, bg, accg[0][ni], 0, 0, 0); \
        accg[1][ni] = __builtin_amdgcn_mfma_f32_16x16x32_bf16(a1, bg, accg[1][ni], 0, 0, 0); \
      }                                                                          \
      _Pragma("unroll")                                                          \
      for (int ni = 0; ni < 4; ++ni){                                            \
        tt_[ni][0] = tr8(wu_of##CUR + 32u*ni);                                   \
        tt_[ni][1] = tr8(wu_of##CUR + 32u*ni + 544u);                            \
      }                                                                          \
      asm volatile("s_waitcnt lgkmcnt(0)");                                      \
      __builtin_amdgcn_sched_barrier(0);                                         \
      _Pragma("unroll")                                                          \
      for (int ni = 0; ni < 4; ++ni){                                            \
        const bf16x8 bu = mk8(tt_[ni][0], tt_[ni][1]);                           \
        accu[0][ni] = __builtin_amdgcn_mfma_f32_16x16x32_bf16(a0, bu, accu[0][ni], 0, 0, 0); \
        accu[1][ni] = __builtin_amdgcn_mfma_f32_16x16x32_bf16(a1, bu, accu[1][ni], 0, 0, 0); \
      }                                                                          \
    }                                                                            \
    if (STAGE_NEXT){                                                             \
      __builtin_amdgcn_sched_barrier(0);                                         \
      asm volatile("s_waitcnt vmcnt(0)");                                        \
      __builtin_amdgcn_sched_barrier(0);                                         \
      st4(&Wgs[NXT][widx0], vg0); st4(&Wus[NXT][widx0], vu0);                    \
      st4(&Wgs[NXT][widx1], vg1); st4(&Wus[NXT][widx1], vu1);                    \
    }                                                                            \
    __syncthreads();                                                             \
  } while (0)

  for (int kt = 0; kt < 64; kt += 2){
    GU_STEP(0, 1, kt, 1);
    GU_STEP(1, 0, kt+1, (kt+1) < 63);
  }
#undef GU_STEP

  const int cr = lane >> 4, cc = lane & 15;
  #pragma unroll
  for (int mi = 0; mi < 2; ++mi)
  #pragma unroll
  for (int ni = 0; ni < 4; ++ni)
  #pragma unroll
  for (int r = 0; r < 4; ++r){
    const int row  = wid*32 + mi*16 + cr*4 + r;
    const int slot = row0 + row;
    if (slot < cnt){
      const float gv = accg[mi][ni][r], uv = accu[mi][ni][r];
      const float a = tws[row] * (gv / (1.f + __expf(-gv))) * uv;
      act[(size_t)(abase + slot)*F_ + f0 + ni*16 + cc] = f2bf(a);
    }
  }
}

// ---------------- K4: down GEMM (2-phase pipelined), atomicAdd into out ----------------
// 4096 blocks, XCD-swizzled: bid = ((e>>3)*256 + dt*16 + tt)*8 + (e&7).
// Weight LDS tile: row-major [k=0..31][d=0..127], stride 136, double-buffered.
__global__ __launch_bounds__(256) void k_down(
    const u16* __restrict__ act, const float* __restrict__ wd,
    const int* __restrict__ counts, const int* __restrict__ eidx,
    float* __restrict__ out)
{
  const int bid = blockIdx.x;
  const int e  = (bid & 7) + 8*(bid >> 11);
  const int rem = (bid >> 3) & 255;
  const int dt = rem >> 4, tt = rem & 15;

  const int cnt = counts[e];
  const int row0 = tt * 128;
  if (row0 >= cnt) return;
  int abase = 0;
  for (int i = 0; i < e; ++i) abase += counts[i];

  const int tid = threadIdx.x, lane = tid & 63, wid = tid >> 6;
  const int d0 = dt * 128;

  __shared__ __align__(16) u16 As[2][4096];
  __shared__ __align__(16) u16 Wds[2][4352];  // [buf][32 rows x stride 136]
  __shared__ int toks[128];

  if (tid < 128){
    int slot = row0 + tid;
    toks[tid] = slot < cnt ? eidx[e*T_ + slot] : -1;
  }
  __syncthreads();

  const int rA = wid*32 + (lane >> 2);
  const int rB = rA + 16;
  const int gA = (lane & 3) ^ (rA & 3);
  const int gB = (lane & 3) ^ (rB & 3);
  const u16* srcA = act + (size_t)(abase + row0 + rA)*F_ + 8*gA;
  const u16* srcB = act + (size_t)(abase + row0 + rB)*F_ + 8*gB;
  void* dstA0 = (void*)&As[0][(wid*32    )*32];
  void* dstB0 = (void*)&As[0][(wid*32 +16)*32];
  void* dstA1 = (void*)&As[1][(wid*32    )*32];
  void* dstB1 = (void*)&As[1][(wid*32 +16)*32];

  // W staging: thread covers k = kc0 + {0,8,16,24}, d-chunk dl4
  const int kc0 = tid >> 5, dl4 = (tid & 31) * 4;
  const size_t wofs = (size_t)e * F_ * D_ + (size_t)kc0 * D_ + d0 + dl4;
  const u32 wix0 = (u32)(kc0*136 + dl4);
  const u32 wix1 = wix0 + 8u*136u;
  const u32 wix2 = wix0 + 16u*136u;
  const u32 wix3 = wix0 + 24u*136u;

  const int p_ = lane & 15, g_ = lane >> 4;
  const u32 trb = (u32)((8*g_ + (p_ >> 2))*136 + 4*(p_ & 3)) * 2u;
  const u32 wd_of0 = lds_off(&Wds[0][0]) + trb;
  const u32 wd_of1 = lds_off(&Wds[1][0]) + trb;

  const int axor = g_ ^ (lane & 3);
  const u32 aoff0 = (u32)(wid*32 + p_)*32 + 8u*(u32)axor;
  const u32 aoff1 = aoff0 + 512;

  f32x4 acc[2][8] = {};
  float4 wv0, wv1, wv2, wv3;

  // prologue: stage kt=0 into buf 0
  gload16(srcA, dstA0);
  gload16(srcB, dstB0);
  {
    const float* pw_ = wd + wofs;
    wv0 = *(const float4*)pw_;
    wv1 = *(const float4*)(pw_ + 8*D_);
    wv2 = *(const float4*)(pw_ + 16*D_);
    wv3 = *(const float4*)(pw_ + 24*D_);
  }
  __builtin_amdgcn_sched_barrier(0);
  asm volatile("s_waitcnt vmcnt(0)");
  __builtin_amdgcn_sched_barrier(0);
  st4(&Wds[0][wix0], wv0); st4(&Wds[0][wix1], wv1);
  st4(&Wds[0][wix2], wv2); st4(&Wds[0][wix3], wv3);
  __syncthreads();

#define DN_STEP(CUR, NXT, KT, STAGE_NEXT) do {                                   \
    if (STAGE_NEXT){                                                             \
      const int kb2 = ((KT)+1) << 5;                                             \
      gload16(srcA + kb2, dstA##NXT);                                            \
      gload16(srcB + kb2, dstB##NXT);                                            \
      const float* pw_ = wd + wofs + (size_t)kb2 * D_;                           \
      wv0 = *(const float4*)pw_;                                                 \
      wv1 = *(const float4*)(pw_ + 8*D_);                                        \
      wv2 = *(const float4*)(pw_ + 16*D_);                                       \
      wv3 = *(const float4*)(pw_ + 24*D_);                                       \
    }                                                                            \
    {                                                                            \
      const bf16x8 a0 = *(const bf16x8*)&As[CUR][aoff0];                         \
      const bf16x8 a1 = *(const bf16x8*)&As[CUR][aoff1];                         \
      u32x2 tb[4][2];                                                            \
      _Pragma("unroll")                                                          \
      for (int ni = 0; ni < 4; ++ni){                                            \
        tb[ni][0] = tr8(wd_of##CUR + 32u*ni);                                    \
        tb[ni][1] = tr8(wd_of##CUR + 32u*ni + 1088u);                            \
      }                                                                          \
      asm volatile("s_waitcnt lgkmcnt(0)");                                      \
      __builtin_amdgcn_sched_barrier(0);                                         \
      _Pragma("unroll")                                                          \
      for (int ni = 0; ni < 4; ++ni){                                            \
        const bf16x8 b = mk8(tb[ni][0], tb[ni][1]);                              \
        acc[0][ni] = __builtin_amdgcn_mfma_f32_16x16x32_bf16(a0, b, acc[0][ni], 0, 0, 0); \
        acc[1][ni] = __builtin_amdgcn_mfma_f32_16x16x32_bf16(a1, b, acc[1][ni], 0, 0, 0); \
      }                                                                          \
      _Pragma("unroll")                                                          \
      for (int ni = 0; ni < 4; ++ni){                                            \
        tb[ni][0] = tr8(wd_of##CUR + 128u + 32u*ni);                             \
        tb[ni][1] = tr8(wd_of##CUR + 128u + 32u*ni + 1088u);                     \
      }                                                                          \
      asm volatile("s_waitcnt lgkmcnt(0)");                                      \
      __builtin_amdgcn_sched_barrier(0);                                         \
      _Pragma("unroll")                                                          \
      for (int ni = 0; ni < 4; ++ni){                                            \
        const bf16x8 b = mk8(tb[ni][0], tb[ni][1]);                              \
        acc[0][ni+4] = __builtin_amdgcn_mfma_f32_16x16x32_bf16(a0, b, acc[0][ni+4], 0, 0, 0); \
        acc[1][ni+4] = __builtin_amdgcn_mfma_f32_16x16x32_bf16(a1, b, acc[1][ni+4], 0, 0, 0); \
      }                                                                          \
    }                                                                            \
    if (STAGE_NEXT){                                                             \
      __builtin_amdgcn_sched_barrier(0);                                         \
      asm volatile("s_waitcnt vmcnt(0)");                                        \
      __builtin_amdgcn_sched_barrier(0);                                         \
      st4(&Wds[NXT][wix0], wv0); st4(&Wds[NXT][wix1], wv1);                      \
      st4(&Wds[NXT][wix2], wv2); st4(&Wds[NXT][wix3], wv3);                      \
    }                                                                            \
    __syncthreads();                                                             \
  } while (0)

  for (int kt = 0; kt < 16; kt += 2){
    DN_STEP(0, 1, kt, 1);
    DN_STEP(1, 0, kt+1, (kt+1) < 15);
  }
#undef DN_STEP

  const int cr = lane >> 4, cc = lane & 15;
  #pragma unroll
  for (int mi = 0; mi < 2; ++mi)
  #pragma unroll
  for (int ni = 0; ni < 8; ++ni)
  #pragma unroll
  for (int r = 0; r < 4; ++r){
    const int row = wid*32 + mi*16 + cr*4 + r;
    const int tok = toks[row];
    if (tok >= 0)
      atomicAdd(out + (size_t)tok*D_ + d0 + ni*16 + cc, acc[mi][ni][r]);
  }
}

extern "C" void kernel_launch(void* const* d_in, const int* in_sizes, int n_in,
                              void* d_out, int out_size, void* d_ws, size_t ws_size,
                              hipStream_t stream)
{
  (void)in_sizes; (void)n_in; (void)out_size; (void)ws_size;
  const float* x     = (const float*)d_in[0];
  const float* nw    = (const float*)d_in[1];
  const float* gw    = (const float*)d_in[2];
  const float* wgate = (const float*)d_in[3];
  const float* wup   = (const float*)d_in[4];
  const float* wdown = (const float*)d_in[5];
  float* out = (float*)d_out;

  char* ws = (char*)d_ws;
  u16*   h      = (u16*)(ws);                       // 8,388,608 B
  u16*   act    = (u16*)(ws + 8388608);             // 8,519,680 B
  int*   counts = (int*)(ws + 16908288);            // 64 B
  int*   eidx   = (int*)(ws + 16908352);            // 131,072 B
  float* ew     = (float*)(ws + 17039424);          // 131,072 B

  hipMemsetAsync(counts, 0, 64, stream);
  k_norm_router<<<T_, 256, 0, stream>>>(x, nw, gw, h, counts, eidx, ew);
  k_copy<<<(T_*D_)/4/256, 256, 0, stream>>>((const float4*)x, (float4*)out);
  k_gateup<<<2048, 256, 0, stream>>>(h, wgate, wup, counts, eidx, ew, act);
  k_down<<<4096, 256, 0, stream>>>(act, wdown, counts, eidx, out);
}

// Round 4
// 297.778 us; speedup vs baseline: 1.8683x; 1.1437x over previous
//
#include <hip/hip_runtime.h>
#include <cstdint>
#include <cstddef>

#define T_ 2048
#define D_ 2048
#define E_ 16
#define F_ 512

typedef unsigned short u16;
typedef unsigned int u32;
typedef __attribute__((ext_vector_type(8))) short bf16x8;
typedef __attribute__((ext_vector_type(4))) short bf16x4;
typedef __attribute__((ext_vector_type(4))) float f32x4;
typedef __attribute__((ext_vector_type(2))) u32 u32x2;
typedef __attribute__((ext_vector_type(8))) u16 u16x8;

__device__ __forceinline__ u16 f2bf(float f){
  union { float f; u32 u; } c; c.f = f;
  return (u16)((c.u + 0x7FFFu + ((c.u >> 16) & 1u)) >> 16);
}

__device__ __forceinline__ void gload16(const void* g, void* l){
  __builtin_amdgcn_global_load_lds((const __attribute__((address_space(1))) void*)g,
                                   (__attribute__((address_space(3))) void*)l,
                                   16, 0, 0);
}

__device__ __forceinline__ u32 lds_off(const void* p){
  return (u32)(uintptr_t)(const __attribute__((address_space(3))) void*)p;
}

__device__ __forceinline__ u32x2 tr8(u32 addr){
  u32x2 r;
  asm volatile("ds_read_b64_tr_b16 %0, %1" : "=v"(r) : "v"(addr));
  return r;
}

__device__ __forceinline__ bf16x8 mk8(u32x2 lo, u32x2 hi){
  bf16x4 a = __builtin_bit_cast(bf16x4, lo);
  bf16x4 b = __builtin_bit_cast(bf16x4, hi);
  return __builtin_shufflevector(a, b, 0,1,2,3,4,5,6,7);
}

// fp32x4 -> bf16x4 (RNE) via v_cvt_pk_bf16_f32, then 8B LDS store
__device__ __forceinline__ void st4(u16* p, float4 v){
  u32 lo, hi;
  asm("v_cvt_pk_bf16_f32 %0, %1, %2" : "=v"(lo) : "v"(v.x), "v"(v.y));
  asm("v_cvt_pk_bf16_f32 %0, %1, %2" : "=v"(hi) : "v"(v.z), "v"(v.w));
  u32x2 u = {lo, hi};
  *(u32x2*)p = u;
}

// ---------------- K1: rmsnorm + router (fp32) + scatter + residual copy ----------------
__global__ __launch_bounds__(256) void k_norm_router(
    const float* __restrict__ x, const float* __restrict__ nw, const float* __restrict__ gw,
    u16* __restrict__ h, int* __restrict__ counts, int* __restrict__ eidx, float* __restrict__ ew,
    float* __restrict__ out)
{
  const int t = blockIdx.x, tid = threadIdx.x;
  const int lane = tid & 63, wid = tid >> 6;
  const int d0 = tid * 8;
  const float4 v0 = *(const float4*)(x + (size_t)t*D_ + d0);
  const float4 v1 = *(const float4*)(x + (size_t)t*D_ + d0 + 4);
  // residual copy
  *(float4*)(out + (size_t)t*D_ + d0)     = v0;
  *(float4*)(out + (size_t)t*D_ + d0 + 4) = v1;
  float hv[8] = {v0.x, v0.y, v0.z, v0.w, v1.x, v1.y, v1.z, v1.w};
  float ss = 0.f;
  #pragma unroll
  for (int j = 0; j < 8; ++j) ss += hv[j]*hv[j];
  #pragma unroll
  for (int o = 32; o; o >>= 1) ss += __shfl_xor(ss, o);
  __shared__ float sred[4];
  __shared__ float red16[4][16];
  __shared__ float lf[16];
  if (lane == 0) sred[wid] = ss;
  __syncthreads();
  const float rstd = rsqrtf((sred[0]+sred[1]+sred[2]+sred[3]) * (1.f/(float)D_) + 1e-6f);
  const float4 w0 = *(const float4*)(nw + d0);
  const float4 w1 = *(const float4*)(nw + d0 + 4);
  const float wv[8] = {w0.x,w0.y,w0.z,w0.w,w1.x,w1.y,w1.z,w1.w};
  #pragma unroll
  for (int j = 0; j < 8; ++j) hv[j] = hv[j] * rstd * wv[j];
  u16x8 hb;
  #pragma unroll
  for (int j = 0; j < 8; ++j) hb[j] = f2bf(hv[j]);
  *(u16x8*)(h + (size_t)t*D_ + d0) = hb;

  float lg[16];
  #pragma unroll
  for (int e = 0; e < 16; ++e){
    const float4 g0 = *(const float4*)(gw + e*D_ + d0);
    const float4 g1 = *(const float4*)(gw + e*D_ + d0 + 4);
    lg[e] = hv[0]*g0.x + hv[1]*g0.y + hv[2]*g0.z + hv[3]*g0.w
          + hv[4]*g1.x + hv[5]*g1.y + hv[6]*g1.z + hv[7]*g1.w;
  }
  #pragma unroll
  for (int e = 0; e < 16; ++e){
    #pragma unroll
    for (int o = 32; o; o >>= 1) lg[e] += __shfl_xor(lg[e], o);
  }
  if (lane == 0){
    #pragma unroll
    for (int e = 0; e < 16; ++e) red16[wid][e] = lg[e];
  }
  __syncthreads();
  if (tid < 16) lf[tid] = red16[0][tid] + red16[1][tid] + red16[2][tid] + red16[3][tid];
  __syncthreads();
  if (tid == 0){
    float l[16];
    #pragma unroll
    for (int e = 0; e < 16; ++e) l[e] = lf[e];
    int sel[4]; float sv[4]; u32 used = 0;
    for (int k = 0; k < 4; ++k){
      float b = -3.4e38f; int bi = 0;
      for (int e = 0; e < 16; ++e)
        if (!((used >> e) & 1u) && l[e] > b){ b = l[e]; bi = e; }
      used |= 1u << bi; sel[k] = bi; sv[k] = b;
    }
    float ex[4]; float s = 0.f;
    for (int k = 0; k < 4; ++k){ ex[k] = __expf(sv[k] - sv[0]); s += ex[k]; }
    const float inv = 1.f / s;
    for (int k = 0; k < 4; ++k){
      const int e = sel[k];
      const int pos = atomicAdd(&counts[e], 1);
      eidx[e*T_ + pos] = t;
      ew[e*T_ + pos] = ex[k] * inv;
    }
  }
}

// ---------------- K3: gate/up GEMM + silu*up (2-phase pipelined, TT=64) ----------------
// grid 4096: bid = ((e>>3)*256 + ft*32 + tt)*8 + (e&7); 64 tok x 64 F per block.
__global__ __launch_bounds__(256, 4) void k_gateup(
    const u16* __restrict__ h, const float* __restrict__ wg, const float* __restrict__ wu,
    const int* __restrict__ counts, const int* __restrict__ eidx, const float* __restrict__ ew,
    u16* __restrict__ act)
{
  const int bid = blockIdx.x;
  const int e  = (bid & 7) + 8*(bid >> 11);
  const int rem = (bid >> 3) & 255;
  const int ft = rem >> 5, tt = rem & 31;

  const int cnt = counts[e];
  const int row0 = tt * 64;
  if (row0 >= cnt) return;
  int abase = 0;
  for (int i = 0; i < e; ++i) abase += counts[i];

  const int tid = threadIdx.x, lane = tid & 63, wid = tid >> 6;
  const int f0 = ft * 64;

  __shared__ __align__(16) u16 Xs[2][2048];   // [buf][64 rows x 32 k]
  __shared__ __align__(16) u16 Wgs[2][2176];  // [buf][32 rows x stride 68]
  __shared__ __align__(16) u16 Wus[2][2176];
  __shared__ int   toks[64];
  __shared__ float tws[64];

  if (tid < 64){
    int slot = row0 + tid;
    int cs = slot < cnt ? slot : (cnt - 1);
    toks[tid] = eidx[e*T_ + cs];
    tws[tid]  = slot < cnt ? ew[e*T_ + slot] : 0.f;
  }
  __syncthreads();

  // X staging: thread stages row rt=tid>>2, 16B chunk ct=tid&3, source chunk XOR'd by row
  const int rt = tid >> 2, ct = tid & 3;
  const u16* srcX = h + (size_t)toks[rt]*D_ + 8*(ct ^ (rt & 3));
  void* dstX0 = (void*)&Xs[0][(wid*16)*32];
  void* dstX1 = (void*)&Xs[1][(wid*16)*32];

  // W staging: thread -> (k0c, f40) and (k0c+16, f40)
  const int k0c = tid >> 4, f40 = (tid & 15) * 4;
  const size_t wofs = (size_t)e * D_ * F_ + (size_t)k0c * F_ + f0 + f40;
  const u32 widx0 = (u32)(k0c*68 + f40);
  const u32 widx1 = widx0 + 16u*68u;

  // tr-read lane base
  const int p_ = lane & 15, g_ = lane >> 4;
  const u32 trb = (u32)((8*g_ + (p_ >> 2))*68 + 4*(p_ & 3)) * 2u;
  const u32 wg_of0 = lds_off(&Wgs[0][0]) + trb;
  const u32 wg_of1 = lds_off(&Wgs[1][0]) + trb;
  const u32 wu_of0 = lds_off(&Wus[0][0]) + trb;
  const u32 wu_of1 = lds_off(&Wus[1][0]) + trb;

  // A fragment: row = wid*16 + p_, k-chunk g_, chunk XOR by row
  const u32 aoff = (u32)(wid*16 + p_)*32 + 8u*(u32)(g_ ^ (p_ & 3));

  f32x4 accg[4] = {};
  f32x4 accu[4] = {};
  float4 vg0, vu0, vg1, vu1;

  // prologue: stage kt=0 into buf 0
  gload16(srcX, dstX0);
  {
    const float* pg_ = wg + wofs;
    const float* pu_ = wu + wofs;
    vg0 = *(const float4*)pg_;
    vu0 = *(const float4*)pu_;
    vg1 = *(const float4*)(pg_ + 16*F_);
    vu1 = *(const float4*)(pu_ + 16*F_);
  }
  __builtin_amdgcn_sched_barrier(0);
  asm volatile("s_waitcnt vmcnt(0)");
  __builtin_amdgcn_sched_barrier(0);
  st4(&Wgs[0][widx0], vg0); st4(&Wus[0][widx0], vu0);
  st4(&Wgs[0][widx1], vg1); st4(&Wus[0][widx1], vu1);
  __syncthreads();

#define GU_STEP(CUR, NXT, KT, STAGE_NEXT) do {                                   \
    if (STAGE_NEXT){                                                             \
      const int kb2 = ((KT)+1) << 5;                                             \
      gload16(srcX + kb2, dstX##NXT);                                            \
      const float* pg_ = wg + wofs + (size_t)kb2 * F_;                           \
      const float* pu_ = wu + wofs + (size_t)kb2 * F_;                           \
      vg0 = *(const float4*)pg_;                                                 \
      vu0 = *(const float4*)pu_;                                                 \
      vg1 = *(const float4*)(pg_ + 16*F_);                                       \
      vu1 = *(const float4*)(pu_ + 16*F_);                                       \
    }                                                                            \
    {                                                                            \
      const bf16x8 a0 = *(const bf16x8*)&Xs[CUR][aoff];                          \
      u32x2 tt_[4][2];                                                           \
      _Pragma("unroll")                                                          \
      for (int ni = 0; ni < 4; ++ni){                                            \
        tt_[ni][0] = tr8(wg_of##CUR + 32u*ni);                                   \
        tt_[ni][1] = tr8(wg_of##CUR + 32u*ni + 544u);                            \
      }                                                                          \
      asm volatile("s_waitcnt lgkmcnt(0)");                                      \
      __builtin_amdgcn_sched_barrier(0);                                         \
      _Pragma("unroll")                                                          \
      for (int ni = 0; ni < 4; ++ni){                                            \
        const bf16x8 bg = mk8(tt_[ni][0], tt_[ni][1]);                           \
        accg[ni] = __builtin_amdgcn_mfma_f32_16x16x32_bf16(a0, bg, accg[ni], 0, 0, 0); \
      }                                                                          \
      _Pragma("unroll")                                                          \
      for (int ni = 0; ni < 4; ++ni){                                            \
        tt_[ni][0] = tr8(wu_of##CUR + 32u*ni);                                   \
        tt_[ni][1] = tr8(wu_of##CUR + 32u*ni + 544u);                            \
      }                                                                          \
      asm volatile("s_waitcnt lgkmcnt(0)");                                      \
      __builtin_amdgcn_sched_barrier(0);                                         \
      _Pragma("unroll")                                                          \
      for (int ni = 0; ni < 4; ++ni){                                            \
        const bf16x8 bu = mk8(tt_[ni][0], tt_[ni][1]);                           \
        accu[ni] = __builtin_amdgcn_mfma_f32_16x16x32_bf16(a0, bu, accu[ni], 0, 0, 0); \
      }                                                                          \
    }                                                                            \
    if (STAGE_NEXT){                                                             \
      __builtin_amdgcn_sched_barrier(0);                                         \
      asm volatile("s_waitcnt vmcnt(0)");                                        \
      __builtin_amdgcn_sched_barrier(0);                                         \
      st4(&Wgs[NXT][widx0], vg0); st4(&Wus[NXT][widx0], vu0);                    \
      st4(&Wgs[NXT][widx1], vg1); st4(&Wus[NXT][widx1], vu1);                    \
    }                                                                            \
    __syncthreads();                                                             \
  } while (0)

  for (int kt = 0; kt < 64; kt += 2){
    GU_STEP(0, 1, kt, 1);
    GU_STEP(1, 0, kt+1, (kt+1) < 63);
  }
#undef GU_STEP

  const int cr = lane >> 4, cc = lane & 15;
  #pragma unroll
  for (int ni = 0; ni < 4; ++ni)
  #pragma unroll
  for (int r = 0; r < 4; ++r){
    const int row  = wid*16 + cr*4 + r;
    const int slot = row0 + row;
    if (slot < cnt){
      const float gv = accg[ni][r], uv = accu[ni][r];
      const float a = tws[row] * (gv / (1.f + __expf(-gv))) * uv;
      act[(size_t)(abase + slot)*F_ + f0 + ni*16 + cc] = f2bf(a);
    }
  }
}

// ---------------- K4: down GEMM (2-phase pipelined, TT=64), atomicAdd into out ----------------
// grid 8192: bid = ((e>>3)*512 + dt*32 + tt)*8 + (e&7); 64 tok x 128 d per block.
__global__ __launch_bounds__(256, 4) void k_down(
    const u16* __restrict__ act, const float* __restrict__ wd,
    const int* __restrict__ counts, const int* __restrict__ eidx,
    float* __restrict__ out)
{
  const int bid = blockIdx.x;
  const int e  = (bid & 7) + 8*(bid >> 12);
  const int rem = (bid >> 3) & 511;
  const int dt = rem >> 5, tt = rem & 31;

  const int cnt = counts[e];
  const int row0 = tt * 64;
  if (row0 >= cnt) return;
  int abase = 0;
  for (int i = 0; i < e; ++i) abase += counts[i];

  const int tid = threadIdx.x, lane = tid & 63, wid = tid >> 6;
  const int d0 = dt * 128;

  __shared__ __align__(16) u16 As[2][2048];
  __shared__ __align__(16) u16 Wds[2][4352];  // [buf][32 rows x stride 136]
  __shared__ int toks[64];

  if (tid < 64){
    int slot = row0 + tid;
    toks[tid] = slot < cnt ? eidx[e*T_ + slot] : -1;
  }
  __syncthreads();

  const int rt = tid >> 2, ct = tid & 3;
  const u16* srcX = act + (size_t)(abase + row0 + rt)*F_ + 8*(ct ^ (rt & 3));
  void* dstX0 = (void*)&As[0][(wid*16)*32];
  void* dstX1 = (void*)&As[1][(wid*16)*32];

  // W staging: thread covers k = kc0 + {0,8,16,24}, d-chunk dl4
  const int kc0 = tid >> 5, dl4 = (tid & 31) * 4;
  const size_t wofs = (size_t)e * F_ * D_ + (size_t)kc0 * D_ + d0 + dl4;
  const u32 wix0 = (u32)(kc0*136 + dl4);
  const u32 wix1 = wix0 + 8u*136u;
  const u32 wix2 = wix0 + 16u*136u;
  const u32 wix3 = wix0 + 24u*136u;

  const int p_ = lane & 15, g_ = lane >> 4;
  const u32 trb = (u32)((8*g_ + (p_ >> 2))*136 + 4*(p_ & 3)) * 2u;
  const u32 wd_of0 = lds_off(&Wds[0][0]) + trb;
  const u32 wd_of1 = lds_off(&Wds[1][0]) + trb;

  const u32 aoff = (u32)(wid*16 + p_)*32 + 8u*(u32)(g_ ^ (p_ & 3));

  f32x4 acc[8] = {};
  float4 wv0, wv1, wv2, wv3;

  gload16(srcX, dstX0);
  {
    const float* pw_ = wd + wofs;
    wv0 = *(const float4*)pw_;
    wv1 = *(const float4*)(pw_ + 8*D_);
    wv2 = *(const float4*)(pw_ + 16*D_);
    wv3 = *(const float4*)(pw_ + 24*D_);
  }
  __builtin_amdgcn_sched_barrier(0);
  asm volatile("s_waitcnt vmcnt(0)");
  __builtin_amdgcn_sched_barrier(0);
  st4(&Wds[0][wix0], wv0); st4(&Wds[0][wix1], wv1);
  st4(&Wds[0][wix2], wv2); st4(&Wds[0][wix3], wv3);
  __syncthreads();

#define DN_STEP(CUR, NXT, KT, STAGE_NEXT) do {                                   \
    if (STAGE_NEXT){                                                             \
      const int kb2 = ((KT)+1) << 5;                                             \
      gload16(srcX + kb2, dstX##NXT);                                            \
      const float* pw_ = wd + wofs + (size_t)kb2 * D_;                           \
      wv0 = *(const float4*)pw_;                                                 \
      wv1 = *(const float4*)(pw_ + 8*D_);                                        \
      wv2 = *(const float4*)(pw_ + 16*D_);                                       \
      wv3 = *(const float4*)(pw_ + 24*D_);                                       \
    }                                                                            \
    {                                                                            \
      const bf16x8 a0 = *(const bf16x8*)&As[CUR][aoff];                          \
      u32x2 tb[4][2];                                                            \
      _Pragma("unroll")                                                          \
      for (int ni = 0; ni < 4; ++ni){                                            \
        tb[ni][0] = tr8(wd_of##CUR + 32u*ni);                                    \
        tb[ni][1] = tr8(wd_of##CUR + 32u*ni + 1088u);                            \
      }                                                                          \
      asm volatile("s_waitcnt lgkmcnt(0)");                                      \
      __builtin_amdgcn_sched_barrier(0);                                         \
      _Pragma("unroll")                                                          \
      for (int ni = 0; ni < 4; ++ni){                                            \
        const bf16x8 b = mk8(tb[ni][0], tb[ni][1]);                              \
        acc[ni] = __builtin_amdgcn_mfma_f32_16x16x32_bf16(a0, b, acc[ni], 0, 0, 0); \
      }                                                                          \
      _Pragma("unroll")                                                          \
      for (int ni = 0; ni < 4; ++ni){                                            \
        tb[ni][0] = tr8(wd_of##CUR + 128u + 32u*ni);                             \
        tb[ni][1] = tr8(wd_of##CUR + 128u + 32u*ni + 1088u);                     \
      }                                                                          \
      asm volatile("s_waitcnt lgkmcnt(0)");                                      \
      __builtin_amdgcn_sched_barrier(0);                                         \
      _Pragma("unroll")                                                          \
      for (int ni = 0; ni < 4; ++ni){                                            \
        const bf16x8 b = mk8(tb[ni][0], tb[ni][1]);                              \
        acc[ni+4] = __builtin_amdgcn_mfma_f32_16x16x32_bf16(a0, b, acc[ni+4], 0, 0, 0); \
      }                                                                          \
    }                                                                            \
    if (STAGE_NEXT){                                                             \
      __builtin_amdgcn_sched_barrier(0);                                         \
      asm volatile("s_waitcnt vmcnt(0)");                                        \
      __builtin_amdgcn_sched_barrier(0);                                         \
      st4(&Wds[NXT][wix0], wv0); st4(&Wds[NXT][wix1], wv1);                      \
      st4(&Wds[NXT][wix2], wv2); st4(&Wds[NXT][wix3], wv3);                      \
    }                                                                            \
    __syncthreads();                                                             \
  } while (0)

  for (int kt = 0; kt < 16; kt += 2){
    DN_STEP(0, 1, kt, 1);
    DN_STEP(1, 0, kt+1, (kt+1) < 15);
  }
#undef DN_STEP

  const int cr = lane >> 4, cc = lane & 15;
  #pragma unroll
  for (int ni = 0; ni < 8; ++ni)
  #pragma unroll
  for (int r = 0; r < 4; ++r){
    const int row = wid*16 + cr*4 + r;
    const int tok = toks[row];
    if (tok >= 0)
      atomicAdd(out + (size_t)tok*D_ + d0 + ni*16 + cc, acc[ni][r]);
  }
}

extern "C" void kernel_launch(void* const* d_in, const int* in_sizes, int n_in,
                              void* d_out, int out_size, void* d_ws, size_t ws_size,
                              hipStream_t stream)
{
  (void)in_sizes; (void)n_in; (void)out_size; (void)ws_size;
  const float* x     = (const float*)d_in[0];
  const float* nw    = (const float*)d_in[1];
  const float* gw    = (const float*)d_in[2];
  const float* wgate = (const float*)d_in[3];
  const float* wup   = (const float*)d_in[4];
  const float* wdown = (const float*)d_in[5];
  float* out = (float*)d_out;

  char* ws = (char*)d_ws;
  u16*   h      = (u16*)(ws);                       // 8,388,608 B
  u16*   act    = (u16*)(ws + 8388608);             // 8,519,680 B
  int*   counts = (int*)(ws + 16908288);            // 64 B
  int*   eidx   = (int*)(ws + 16908352);            // 131,072 B
  float* ew     = (float*)(ws + 17039424);          // 131,072 B

  hipMemsetAsync(counts, 0, 64, stream);
  k_norm_router<<<T_, 256, 0, stream>>>(x, nw, gw, h, counts, eidx, ew, out);
  k_gateup<<<4096, 256, 0, stream>>>(h, wgate, wup, counts, eidx, ew, act);
  k_down<<<8192, 256, 0, stream>>>(act, wdown, counts, eidx, out);
}